// Round 2
// baseline (636.780 us; speedup 1.0000x reference)
//
#include <hip/hip_runtime.h>

#define H_ 64
#define HD_ 32
#define NP 8192
#define NR 16384
#define NC 65536
#define EP 65536
#define NCLS 11

// ---------------- CSR build ----------------
__global__ void k_hist(const int* __restrict__ pass_src, int* __restrict__ deg) {
    int e = blockIdx.x * 256 + threadIdx.x;
    if (e < EP) atomicAdd(&deg[pass_src[e]], 1);
}

__global__ void k_scan(const int* __restrict__ deg, int* __restrict__ off, int* __restrict__ cursor) {
    __shared__ int sums[256];
    int t = threadIdx.x;
    int local[32];
    int s = 0;
#pragma unroll
    for (int i = 0; i < 32; i++) { local[i] = s; s += deg[t * 32 + i]; }
    sums[t] = s;
    __syncthreads();
    for (int ofs = 1; ofs < 256; ofs <<= 1) {
        int u = (t >= ofs) ? sums[t - ofs] : 0;
        __syncthreads();
        sums[t] += u;
        __syncthreads();
    }
    int base = sums[t] - s;
#pragma unroll
    for (int i = 0; i < 32; i++) {
        int v = base + local[i];
        off[t * 32 + i] = v;
        cursor[t * 32 + i] = v;
    }
}

// Pre-resolve (a,b) per edge; pack into one int since NR = 2^14.
__global__ void k_scatter(const int* __restrict__ pass_src, const int* __restrict__ pass_dst,
                          const int* __restrict__ out_src, const int* __restrict__ in_dst,
                          int* __restrict__ cursor, int* __restrict__ csr_ab) {
    int e = blockIdx.x * 256 + threadIdx.x;
    if (e < EP) {
        int p = pass_src[e];
        int c = pass_dst[e];
        int a = out_src[c];
        int b = in_dst[c];
        int pos = atomicAdd(&cursor[p], 1);
        csr_ab[pos] = (a << 14) | b;
    }
}

// ---------------- FeatureGen: routers -> hidden ----------------
__global__ __launch_bounds__(256) void k_router(const float* __restrict__ op,
                                                const float* __restrict__ w_op, const float* __restrict__ b_op,
                                                const float* __restrict__ w_fr, const float* __restrict__ b_fr,
                                                float* __restrict__ hidden) {
    __shared__ float s_wop[4 * 64];
    __shared__ float s_wfr[64 * 64];
    __shared__ float s_bop[64], s_bfr[64];
    __shared__ float s_tmp[16 * 64];
    int t = threadIdx.x;
    if (t < 64) { s_bop[t] = b_op[t]; s_bfr[t] = b_fr[t]; }
    if (t < 256) s_wop[t] = w_op[t];
    for (int i = t; i < 4096; i += 256) s_wfr[i] = w_fr[i];
    __syncthreads();
    int r0 = blockIdx.x * 16;
    for (int idx = t; idx < 16 * 64; idx += 256) {
        int row = idx >> 6, i = idx & 63;
        const float* o = op + (size_t)(r0 + row) * 4;
        float v = s_bop[i] + o[0] * s_wop[i] + o[1] * s_wop[64 + i] + o[2] * s_wop[128 + i] + o[3] * s_wop[192 + i];
        s_tmp[idx] = fmaxf(v, 0.f);
    }
    __syncthreads();
    for (int idx = t; idx < 16 * 64; idx += 256) {
        int row = idx >> 6, j = idx & 63;
        float acc = s_bfr[j];
        const float* tm = s_tmp + row * 64;
#pragma unroll 16
        for (int i = 0; i < 64; i++) acc += tm[i] * s_wfr[i * 64 + j];
        hidden[(size_t)(r0 + row) * 64 + j] = acc;
    }
}

// ---------------- FeatureGen: packets -> packet_feat ----------------
__global__ __launch_bounds__(256) void k_packet(const float* __restrict__ freq, const float* __restrict__ flit,
                                                const float* __restrict__ w_freq, const float* __restrict__ b_freq,
                                                const float* __restrict__ w_flit, const float* __restrict__ b_flit,
                                                const float* __restrict__ w_fp, const float* __restrict__ b_fp,
                                                float* __restrict__ pf) {
    __shared__ float s_wfl[32 * 64];
    __shared__ float s_wfp[128 * 64];
    __shared__ float s_tmp[16 * 128];
    __shared__ float s_wfq[64], s_bfq[64], s_bfl[64], s_bfp[64];
    int t = threadIdx.x;
    if (t < 64) { s_wfq[t] = w_freq[t]; s_bfq[t] = b_freq[t]; s_bfl[t] = b_flit[t]; s_bfp[t] = b_fp[t]; }
    for (int i = t; i < 2048; i += 256) s_wfl[i] = w_flit[i];
    for (int i = t; i < 8192; i += 256) s_wfp[i] = w_fp[i];
    __syncthreads();
    int r0 = blockIdx.x * 16;
    for (int idx = t; idx < 16 * 128; idx += 256) {
        int row = idx >> 7, i = idx & 127;
        float v;
        if (i < 64) {
            v = s_bfq[i] + freq[r0 + row] * s_wfq[i];
        } else {
            int ii = i - 64;
            float acc = s_bfl[ii];
            const float* f = flit + (size_t)(r0 + row) * 32;
#pragma unroll 8
            for (int k = 0; k < 32; k++) acc += f[k] * s_wfl[k * 64 + ii];
            v = acc;
        }
        s_tmp[idx] = fmaxf(v, 0.f);
    }
    __syncthreads();
    for (int idx = t; idx < 16 * 64; idx += 256) {
        int row = idx >> 6, j = idx & 63;
        float acc = s_bfp[j];
        const float* tm = s_tmp + row * 128;
#pragma unroll 16
        for (int i = 0; i < 128; i++) acc += tm[i] * s_wfp[i * 64 + j];
        pf[(size_t)(r0 + row) * 64 + j] = acc;
    }
}

// ---------------- pfeat_t[p][d][h] = (pf @ w_mp + b_mp) transposed ----------------
// Block: 64 packets x (2 d-values x all 64 h).  Bs storage col c holds logical
// jj = ((c&15)<<3)|(c>>4) so compute reads Bs[k][jjl*16+jg] conflict-free.
__global__ __launch_bounds__(256) void k_pfeat(const float* __restrict__ pf, const float* __restrict__ w_mp,
                                               const float* __restrict__ b_mp, float* __restrict__ pfeat_t) {
    __shared__ float As[64][65];
    __shared__ float Bs[64][128];
    int t = threadIdx.x;
    int p0 = blockIdx.x * 64;
    int d0 = blockIdx.y * 2;
    for (int idx = t; idx < 64 * 64; idx += 256) {
        int r = idx >> 6, k = idx & 63;
        As[r][k] = pf[(size_t)(p0 + r) * 64 + k];
    }
    for (int idx = t; idx < 64 * 128; idx += 256) {
        int k = idx >> 7, c = idx & 127;
        int jj = ((c & 15) << 3) | (c >> 4);
        int h = jj >> 1, dd = jj & 1;
        Bs[k][c] = w_mp[(size_t)k * 2048 + h * 32 + d0 + dd];
    }
    __syncthreads();
    int pg = t >> 4, jg = t & 15;
    float acc[4][8] = {};
#pragma unroll 4
    for (int k = 0; k < 64; k++) {
        float a0 = As[pg * 4 + 0][k], a1 = As[pg * 4 + 1][k], a2 = As[pg * 4 + 2][k], a3 = As[pg * 4 + 3][k];
#pragma unroll
        for (int jjl = 0; jjl < 8; jjl++) {
            float b = Bs[k][jjl * 16 + jg];
            acc[0][jjl] = fmaf(a0, b, acc[0][jjl]);
            acc[1][jjl] = fmaf(a1, b, acc[1][jjl]);
            acc[2][jjl] = fmaf(a2, b, acc[2][jjl]);
            acc[3][jjl] = fmaf(a3, b, acc[3][jjl]);
        }
    }
    // logical jj = jg*8+jjl -> h = jg*4 + (jjl>>1), dd = jjl&1
    float bias[8];
#pragma unroll
    for (int jjl = 0; jjl < 8; jjl++) bias[jjl] = b_mp[(jg * 4 + (jjl >> 1)) * 32 + d0 + (jjl & 1)];
#pragma unroll
    for (int pp = 0; pp < 4; pp++) {
#pragma unroll
        for (int dd = 0; dd < 2; dd++) {
            float4 v;
            v.x = acc[pp][0 + dd] + bias[0 + dd];
            v.y = acc[pp][2 + dd] + bias[2 + dd];
            v.z = acc[pp][4 + dd] + bias[4 + dd];
            v.w = acc[pp][6 + dd] + bias[6 + dd];
            *(float4*)(pfeat_t + (size_t)(p0 + pg * 4 + pp) * 2048 + (d0 + dd) * 64 + jg * 4) = v;
        }
    }
}

// ---------------- Message passing ----------------
// wave per packet; lane = (hi,d): preg[q].{x..w} = pfeat[p][h=hi*32+q*4+c][d]
// per edge: x rows loaded as per-half-broadcast float4s, 64 FMAs, 1 shfl_xor per output.
__global__ __launch_bounds__(256) void k_mp(const float* __restrict__ pfeat_t, const float* __restrict__ hidden,
                                            const int* __restrict__ off, const int* __restrict__ deg,
                                            const int* __restrict__ csr_ab, float* __restrict__ m) {
    int wid = __builtin_amdgcn_readfirstlane((blockIdx.x << 2) + (threadIdx.x >> 6));
    int lane = threadIdx.x & 63;
    int hi = lane >> 5, d = lane & 31;
    const float4* pr = (const float4*)(pfeat_t + (size_t)wid * 2048) + d * 16 + hi * 8;
    float4 preg[8];
#pragma unroll
    for (int q = 0; q < 8; q++) preg[q] = pr[q];
    int e0 = off[wid];
    int n = deg[wid];
    const float4* hb4 = (const float4*)hidden;
    int pk = (n > 0) ? csr_ab[e0] : 0;
    for (int i = 0; i < n; i++) {
        int pkn = (i + 1 < n) ? csr_ab[e0 + i + 1] : 0;
        int a = pk >> 14, b = pk & 16383;
        const float4* xa = hb4 + a * 16 + hi * 8;
        const float4* xb = hb4 + b * 16 + hi * 8;
        float4 xav[8], xbv[8];
#pragma unroll
        for (int q = 0; q < 8; q++) xav[q] = xa[q];
#pragma unroll
        for (int q = 0; q < 8; q++) xbv[q] = xb[q];
        float vi0 = 0, vi1 = 0, vi2 = 0, vi3 = 0, vo0 = 0, vo1 = 0, vo2 = 0, vo3 = 0;
#pragma unroll
        for (int q = 0; q < 8; q++) {
            vi0 = fmaf(preg[q].x, xav[q].x, vi0);
            vi1 = fmaf(preg[q].y, xav[q].y, vi1);
            vi2 = fmaf(preg[q].z, xav[q].z, vi2);
            vi3 = fmaf(preg[q].w, xav[q].w, vi3);
            vo0 = fmaf(preg[q].x, xbv[q].x, vo0);
            vo1 = fmaf(preg[q].y, xbv[q].y, vo1);
            vo2 = fmaf(preg[q].z, xbv[q].z, vo2);
            vo3 = fmaf(preg[q].w, xbv[q].w, vo3);
        }
        float vin = (vi0 + vi1) + (vi2 + vi3);
        float vout = (vo0 + vo1) + (vo2 + vo3);
        vin += __shfl_xor(vin, 32);
        vout += __shfl_xor(vout, 32);
        if (hi == 0) atomicAdd(&m[(size_t)b * 64 + d], vin);
        else         atomicAdd(&m[(size_t)a * 64 + 32 + d], vout);
        pk = pkn;
    }
}

// ---------------- hidden = relu(hidden + m); zero m (iter0) / fused pooling (final) ----------------
template <int FINAL>
__global__ __launch_bounds__(256) void k_update(float* __restrict__ hidden, float* __restrict__ m,
                                                float* __restrict__ embed) {
    int base = blockIdx.x * 256 + threadIdx.x;
    float4* h4 = (float4*)hidden;
    float4* m4 = (float4*)m;
    float acc = 0.f;
    for (int i = base; i < NR * 16; i += 65536) {
        float4 hv = h4[i];
        float4 mv = m4[i];
        float4 v;
        v.x = fmaxf(hv.x + mv.x, 0.f);
        v.y = fmaxf(hv.y + mv.y, 0.f);
        v.z = fmaxf(hv.z + mv.z, 0.f);
        v.w = fmaxf(hv.w + mv.w, 0.f);
        h4[i] = v;
        if (!FINAL) m4[i] = make_float4(0.f, 0.f, 0.f, 0.f);
        acc += (v.x + v.y) + (v.z + v.w);
    }
    if (FINAL) {
        // acc holds sums of 4-element groups; element-wise embed needs per-column sums.
        // redo per-column: each thread's float4 covers columns (i*4..i*4+3) % 64.
        // Simpler: accumulate per-column partials in LDS.
        __shared__ float red[256];
        // recompute column-wise partials
        float col[4] = {0.f, 0.f, 0.f, 0.f};
        for (int i = base; i < NR * 16; i += 65536) {
            float4 v = h4[i];
            col[0] += v.x; col[1] += v.y; col[2] += v.z; col[3] += v.w;
        }
        int c0 = (base * 4) & 63;  // column of .x (constant across the strided loop: stride 65536*4 % 64 == 0)
        red[threadIdx.x] = col[0];
        __syncthreads();
        // columns: thread t covers columns (t*4 + blockIdx.x*1024) %64 = (t*4)%64 ... use atomic per thread
        atomicAdd(&embed[c0], col[0]);
        atomicAdd(&embed[(c0 + 1) & 63], col[1]);
        atomicAdd(&embed[(c0 + 2) & 63], col[2]);
        atomicAdd(&embed[(c0 + 3) & 63], col[3]);
    }
}

// ---------------- prediction head ----------------
__global__ void k_head(const float* __restrict__ embed,
                       const float* __restrict__ w_h1, const float* __restrict__ b_h1,
                       const float* __restrict__ w_h2, const float* __restrict__ b_h2,
                       const float* __restrict__ w_out, const float* __restrict__ b_out,
                       float* __restrict__ out) {
    __shared__ float e1[64], e2[64];
    int t = threadIdx.x;
    float acc = b_h1[t];
#pragma unroll 16
    for (int k = 0; k < 64; k++) acc += embed[k] * w_h1[k * 64 + t];
    e1[t] = fmaxf(acc, 0.f);
    __syncthreads();
    acc = b_h2[t];
#pragma unroll 16
    for (int k = 0; k < 64; k++) acc += e1[k] * w_h2[k * 64 + t];
    e2[t] = fmaxf(acc, 0.f);
    __syncthreads();
    if (t < NCLS) {
        acc = b_out[t];
#pragma unroll 16
        for (int k = 0; k < 64; k++) acc += e2[k] * w_out[k * NCLS + t];
        out[t] = acc;
    }
}

extern "C" void kernel_launch(void* const* d_in, const int* in_sizes, int n_in,
                              void* d_out, int out_size, void* d_ws, size_t ws_size,
                              hipStream_t stream) {
    const float* freq   = (const float*)d_in[0];
    const float* flit   = (const float*)d_in[1];
    const float* op     = (const float*)d_in[2];
    const int* out_src  = (const int*)d_in[4];
    const int* in_dst   = (const int*)d_in[7];
    const int* pass_src = (const int*)d_in[8];
    const int* pass_dst = (const int*)d_in[9];
    const float* w_freq = (const float*)d_in[10];
    const float* b_freq = (const float*)d_in[11];
    const float* w_flit = (const float*)d_in[12];
    const float* b_flit = (const float*)d_in[13];
    const float* w_op   = (const float*)d_in[14];
    const float* b_op   = (const float*)d_in[15];
    const float* w_fp   = (const float*)d_in[18];
    const float* b_fp   = (const float*)d_in[19];
    const float* w_fr   = (const float*)d_in[20];
    const float* b_fr   = (const float*)d_in[21];
    const float* w_mp   = (const float*)d_in[24];
    const float* b_mp   = (const float*)d_in[25];
    const float* w_h1   = (const float*)d_in[26];
    const float* b_h1   = (const float*)d_in[27];
    const float* w_h2   = (const float*)d_in[28];
    const float* b_h2   = (const float*)d_in[29];
    const float* w_out  = (const float*)d_in[30];
    const float* b_out  = (const float*)d_in[31];
    float* out = (float*)d_out;

    char* ws = (char*)d_ws;
    float* pfeat_t     = (float*)(ws);                         // 64 MB
    float* hidden      = (float*)(ws + 67108864);              // 4 MB
    float* m           = (float*)(ws + 71303168);              // 4 MB
    float* embed       = (float*)(ws + 75497472);              // 256 B
    float* packet_feat = (float*)(ws + 75497728);              // 2 MB
    int*   deg         = (int*)  (ws + 77594880);              // 32 KB
    int*   off         = (int*)  (ws + 77627648);              // 32 KB
    int*   cursor      = (int*)  (ws + 77660416);              // 32 KB
    int*   csr_ab      = (int*)  (ws + 77693184);              // 256 KB

    // CSR build
    hipMemsetAsync(deg, 0, NP * sizeof(int), stream);
    k_hist<<<EP / 256, 256, 0, stream>>>(pass_src, deg);
    k_scan<<<1, 256, 0, stream>>>(deg, off, cursor);
    k_scatter<<<EP / 256, 256, 0, stream>>>(pass_src, pass_dst, out_src, in_dst, cursor, csr_ab);

    // Features
    k_packet<<<NP / 16, 256, 0, stream>>>(freq, flit, w_freq, b_freq, w_flit, b_flit, w_fp, b_fp, packet_feat);
    k_pfeat<<<dim3(NP / 64, 16), 256, 0, stream>>>(packet_feat, w_mp, b_mp, pfeat_t);
    k_router<<<NR / 16, 256, 0, stream>>>(op, w_op, b_op, w_fr, b_fr, hidden);

    // MP iteration 0 (update<0> re-zeroes m for iteration 1)
    hipMemsetAsync(m, 0, NR * 64 * sizeof(float) + 64 * sizeof(float), stream);  // m + embed
    k_mp<<<NP / 4, 256, 0, stream>>>(pfeat_t, hidden, off, deg, csr_ab, m);
    k_update<0><<<256, 256, 0, stream>>>(hidden, m, embed);

    // MP iteration 1
    k_mp<<<NP / 4, 256, 0, stream>>>(pfeat_t, hidden, off, deg, csr_ab, m);
    k_update<1><<<256, 256, 0, stream>>>(hidden, m, embed);

    // Head
    k_head<<<1, 64, 0, stream>>>(embed, w_h1, b_h1, w_h2, b_h2, w_out, b_out, out);
}

// Round 3
// 236.662 us; speedup vs baseline: 2.6907x; 2.6907x over previous
//
#include <hip/hip_runtime.h>

#define H_ 64
#define HD_ 32
#define NP 8192
#define NR 16384
#define NC 65536
#define EP 65536
#define NCLS 11

// ---------------- CSR build ----------------
__global__ void k_hist(const int* __restrict__ pass_src, int* __restrict__ deg) {
    int e = blockIdx.x * 256 + threadIdx.x;
    if (e < EP) atomicAdd(&deg[pass_src[e]], 1);
}

__global__ void k_scan(const int* __restrict__ deg, int* __restrict__ off, int* __restrict__ cursor) {
    __shared__ int sums[256];
    int t = threadIdx.x;
    int local[32];
    int s = 0;
#pragma unroll
    for (int i = 0; i < 32; i++) { local[i] = s; s += deg[t * 32 + i]; }
    sums[t] = s;
    __syncthreads();
    for (int ofs = 1; ofs < 256; ofs <<= 1) {
        int u = (t >= ofs) ? sums[t - ofs] : 0;
        __syncthreads();
        sums[t] += u;
        __syncthreads();
    }
    int base = sums[t] - s;
#pragma unroll
    for (int i = 0; i < 32; i++) {
        int v = base + local[i];
        off[t * 32 + i] = v;
        cursor[t * 32 + i] = v;
    }
}

// Pre-resolve (a,b) per edge; pack into one int since NR = 2^14.
__global__ void k_scatter(const int* __restrict__ pass_src, const int* __restrict__ pass_dst,
                          const int* __restrict__ out_src, const int* __restrict__ in_dst,
                          int* __restrict__ cursor, int* __restrict__ csr_ab) {
    int e = blockIdx.x * 256 + threadIdx.x;
    if (e < EP) {
        int p = pass_src[e];
        int c = pass_dst[e];
        int a = out_src[c];
        int b = in_dst[c];
        int pos = atomicAdd(&cursor[p], 1);
        csr_ab[pos] = (a << 14) | b;
    }
}

// ---------------- FeatureGen: routers -> hidden ----------------
__global__ __launch_bounds__(256) void k_router(const float* __restrict__ op,
                                                const float* __restrict__ w_op, const float* __restrict__ b_op,
                                                const float* __restrict__ w_fr, const float* __restrict__ b_fr,
                                                float* __restrict__ hidden) {
    __shared__ float s_wop[4 * 64];
    __shared__ float s_wfr[64 * 64];
    __shared__ float s_bop[64], s_bfr[64];
    __shared__ float s_tmp[16 * 64];
    int t = threadIdx.x;
    if (t < 64) { s_bop[t] = b_op[t]; s_bfr[t] = b_fr[t]; }
    if (t < 256) s_wop[t] = w_op[t];
    for (int i = t; i < 4096; i += 256) s_wfr[i] = w_fr[i];
    __syncthreads();
    int r0 = blockIdx.x * 16;
    for (int idx = t; idx < 16 * 64; idx += 256) {
        int row = idx >> 6, i = idx & 63;
        const float* o = op + (size_t)(r0 + row) * 4;
        float v = s_bop[i] + o[0] * s_wop[i] + o[1] * s_wop[64 + i] + o[2] * s_wop[128 + i] + o[3] * s_wop[192 + i];
        s_tmp[idx] = fmaxf(v, 0.f);
    }
    __syncthreads();
    for (int idx = t; idx < 16 * 64; idx += 256) {
        int row = idx >> 6, j = idx & 63;
        float acc = s_bfr[j];
        const float* tm = s_tmp + row * 64;
#pragma unroll 16
        for (int i = 0; i < 64; i++) acc += tm[i] * s_wfr[i * 64 + j];
        hidden[(size_t)(r0 + row) * 64 + j] = acc;
    }
}

// ---------------- FeatureGen: packets -> packet_feat ----------------
__global__ __launch_bounds__(256) void k_packet(const float* __restrict__ freq, const float* __restrict__ flit,
                                                const float* __restrict__ w_freq, const float* __restrict__ b_freq,
                                                const float* __restrict__ w_flit, const float* __restrict__ b_flit,
                                                const float* __restrict__ w_fp, const float* __restrict__ b_fp,
                                                float* __restrict__ pf) {
    __shared__ float s_wfl[32 * 64];
    __shared__ float s_wfp[128 * 64];
    __shared__ float s_tmp[16 * 128];
    __shared__ float s_wfq[64], s_bfq[64], s_bfl[64], s_bfp[64];
    int t = threadIdx.x;
    if (t < 64) { s_wfq[t] = w_freq[t]; s_bfq[t] = b_freq[t]; s_bfl[t] = b_flit[t]; s_bfp[t] = b_fp[t]; }
    for (int i = t; i < 2048; i += 256) s_wfl[i] = w_flit[i];
    for (int i = t; i < 8192; i += 256) s_wfp[i] = w_fp[i];
    __syncthreads();
    int r0 = blockIdx.x * 16;
    for (int idx = t; idx < 16 * 128; idx += 256) {
        int row = idx >> 7, i = idx & 127;
        float v;
        if (i < 64) {
            v = s_bfq[i] + freq[r0 + row] * s_wfq[i];
        } else {
            int ii = i - 64;
            float acc = s_bfl[ii];
            const float* f = flit + (size_t)(r0 + row) * 32;
#pragma unroll 8
            for (int k = 0; k < 32; k++) acc += f[k] * s_wfl[k * 64 + ii];
            v = acc;
        }
        s_tmp[idx] = fmaxf(v, 0.f);
    }
    __syncthreads();
    for (int idx = t; idx < 16 * 64; idx += 256) {
        int row = idx >> 6, j = idx & 63;
        float acc = s_bfp[j];
        const float* tm = s_tmp + row * 128;
#pragma unroll 16
        for (int i = 0; i < 128; i++) acc += tm[i] * s_wfp[i * 64 + j];
        pf[(size_t)(r0 + row) * 64 + j] = acc;
    }
}

// ---------------- pfeat_t[p][d][h] = (pf @ w_mp + b_mp) transposed ----------------
__global__ __launch_bounds__(256) void k_pfeat(const float* __restrict__ pf, const float* __restrict__ w_mp,
                                               const float* __restrict__ b_mp, float* __restrict__ pfeat_t) {
    __shared__ float As[64][65];
    __shared__ float Bs[64][128];
    int t = threadIdx.x;
    int p0 = blockIdx.x * 64;
    int d0 = blockIdx.y * 2;
    for (int idx = t; idx < 64 * 64; idx += 256) {
        int r = idx >> 6, k = idx & 63;
        As[r][k] = pf[(size_t)(p0 + r) * 64 + k];
    }
    for (int idx = t; idx < 64 * 128; idx += 256) {
        int k = idx >> 7, c = idx & 127;
        int jj = ((c & 15) << 3) | (c >> 4);
        int h = jj >> 1, dd = jj & 1;
        Bs[k][c] = w_mp[(size_t)k * 2048 + h * 32 + d0 + dd];
    }
    __syncthreads();
    int pg = t >> 4, jg = t & 15;
    float acc[4][8] = {};
#pragma unroll 4
    for (int k = 0; k < 64; k++) {
        float a0 = As[pg * 4 + 0][k], a1 = As[pg * 4 + 1][k], a2 = As[pg * 4 + 2][k], a3 = As[pg * 4 + 3][k];
#pragma unroll
        for (int jjl = 0; jjl < 8; jjl++) {
            float b = Bs[k][jjl * 16 + jg];
            acc[0][jjl] = fmaf(a0, b, acc[0][jjl]);
            acc[1][jjl] = fmaf(a1, b, acc[1][jjl]);
            acc[2][jjl] = fmaf(a2, b, acc[2][jjl]);
            acc[3][jjl] = fmaf(a3, b, acc[3][jjl]);
        }
    }
    float bias[8];
#pragma unroll
    for (int jjl = 0; jjl < 8; jjl++) bias[jjl] = b_mp[(jg * 4 + (jjl >> 1)) * 32 + d0 + (jjl & 1)];
#pragma unroll
    for (int pp = 0; pp < 4; pp++) {
#pragma unroll
        for (int dd = 0; dd < 2; dd++) {
            float4 v;
            v.x = acc[pp][0 + dd] + bias[0 + dd];
            v.y = acc[pp][2 + dd] + bias[2 + dd];
            v.z = acc[pp][4 + dd] + bias[4 + dd];
            v.w = acc[pp][6 + dd] + bias[6 + dd];
            *(float4*)(pfeat_t + (size_t)(p0 + pg * 4 + pp) * 2048 + (d0 + dd) * 64 + jg * 4) = v;
        }
    }
}

// ---------------- Message passing ----------------
__global__ __launch_bounds__(256) void k_mp(const float* __restrict__ pfeat_t, const float* __restrict__ hidden,
                                            const int* __restrict__ off, const int* __restrict__ deg,
                                            const int* __restrict__ csr_ab, float* __restrict__ m) {
    int wid = __builtin_amdgcn_readfirstlane((blockIdx.x << 2) + (threadIdx.x >> 6));
    int lane = threadIdx.x & 63;
    int hi = lane >> 5, d = lane & 31;
    const float4* pr = (const float4*)(pfeat_t + (size_t)wid * 2048) + d * 16 + hi * 8;
    float4 preg[8];
#pragma unroll
    for (int q = 0; q < 8; q++) preg[q] = pr[q];
    int e0 = off[wid];
    int n = deg[wid];
    const float4* hb4 = (const float4*)hidden;
    int pk = (n > 0) ? csr_ab[e0] : 0;
    for (int i = 0; i < n; i++) {
        int pkn = (i + 1 < n) ? csr_ab[e0 + i + 1] : 0;
        int a = pk >> 14, b = pk & 16383;
        const float4* xa = hb4 + a * 16 + hi * 8;
        const float4* xb = hb4 + b * 16 + hi * 8;
        float4 xav[8], xbv[8];
#pragma unroll
        for (int q = 0; q < 8; q++) xav[q] = xa[q];
#pragma unroll
        for (int q = 0; q < 8; q++) xbv[q] = xb[q];
        float vi0 = 0, vi1 = 0, vi2 = 0, vi3 = 0, vo0 = 0, vo1 = 0, vo2 = 0, vo3 = 0;
#pragma unroll
        for (int q = 0; q < 8; q++) {
            vi0 = fmaf(preg[q].x, xav[q].x, vi0);
            vi1 = fmaf(preg[q].y, xav[q].y, vi1);
            vi2 = fmaf(preg[q].z, xav[q].z, vi2);
            vi3 = fmaf(preg[q].w, xav[q].w, vi3);
            vo0 = fmaf(preg[q].x, xbv[q].x, vo0);
            vo1 = fmaf(preg[q].y, xbv[q].y, vo1);
            vo2 = fmaf(preg[q].z, xbv[q].z, vo2);
            vo3 = fmaf(preg[q].w, xbv[q].w, vo3);
        }
        float vin = (vi0 + vi1) + (vi2 + vi3);
        float vout = (vo0 + vo1) + (vo2 + vo3);
        vin += __shfl_xor(vin, 32);
        vout += __shfl_xor(vout, 32);
        if (hi == 0) atomicAdd(&m[(size_t)b * 64 + d], vin);
        else         atomicAdd(&m[(size_t)a * 64 + 32 + d], vout);
        pk = pkn;
    }
}

// ---------------- update: hidden = relu(hidden + m) ----------------
// Non-final: streaming, also re-zeroes m. Grid 1024 (one float4/thread).
__global__ __launch_bounds__(256) void k_update0(float* __restrict__ hidden, float* __restrict__ m) {
    int i = blockIdx.x * 256 + threadIdx.x;  // exactly NR*16 threads
    float4* h4 = (float4*)hidden;
    float4* m4 = (float4*)m;
    float4 hv = h4[i];
    float4 mv = m4[i];
    float4 v;
    v.x = fmaxf(hv.x + mv.x, 0.f);
    v.y = fmaxf(hv.y + mv.y, 0.f);
    v.z = fmaxf(hv.z + mv.z, 0.f);
    v.w = fmaxf(hv.w + mv.w, 0.f);
    h4[i] = v;
    m4[i] = make_float4(0.f, 0.f, 0.f, 0.f);
}

// Final: hidden never read again -> no store; fused column-sum pooling into
// line-padded embed (embed[c*16], 64B apart -> atomics hit distinct L2 lines).
// Grid 128. Column of float4 element k is ((i*4)+k)&63, constant per thread.
__global__ __launch_bounds__(256) void k_update1(const float* __restrict__ hidden, const float* __restrict__ m,
                                                 float* __restrict__ embed) {
    int t = threadIdx.x;
    int base = blockIdx.x * 256 + t;
    const float4* h4 = (const float4*)hidden;
    const float4* m4 = (const float4*)m;
    float col[4] = {0.f, 0.f, 0.f, 0.f};
    for (int i = base; i < NR * 16; i += 128 * 256) {
        float4 hv = h4[i];
        float4 mv = m4[i];
        col[0] += fmaxf(hv.x + mv.x, 0.f);
        col[1] += fmaxf(hv.y + mv.y, 0.f);
        col[2] += fmaxf(hv.z + mv.z, 0.f);
        col[3] += fmaxf(hv.w + mv.w, 0.f);
    }
    // lanes L and L^16 (and L^32) cover the same 4 columns -> butterfly
#pragma unroll
    for (int k = 0; k < 4; k++) {
        col[k] += __shfl_xor(col[k], 16);
        col[k] += __shfl_xor(col[k], 32);
    }
    __shared__ float scol[4][64];
    int w = t >> 6, lane = t & 63;
    if (lane < 16) {
#pragma unroll
        for (int k = 0; k < 4; k++) scol[w][lane * 4 + k] = col[k];
    }
    __syncthreads();
    if (t < 64) {
        float s = scol[0][t] + scol[1][t] + scol[2][t] + scol[3][t];
        atomicAdd(&embed[t * 16], s);
    }
}

// ---------------- prediction head (embed is line-padded: stride 16 floats) ----------------
__global__ void k_head(const float* __restrict__ embed,
                       const float* __restrict__ w_h1, const float* __restrict__ b_h1,
                       const float* __restrict__ w_h2, const float* __restrict__ b_h2,
                       const float* __restrict__ w_out, const float* __restrict__ b_out,
                       float* __restrict__ out) {
    __shared__ float e1[64], e2[64];
    int t = threadIdx.x;
    float acc = b_h1[t];
#pragma unroll 16
    for (int k = 0; k < 64; k++) acc += embed[k * 16] * w_h1[k * 64 + t];
    e1[t] = fmaxf(acc, 0.f);
    __syncthreads();
    acc = b_h2[t];
#pragma unroll 16
    for (int k = 0; k < 64; k++) acc += e1[k] * w_h2[k * 64 + t];
    e2[t] = fmaxf(acc, 0.f);
    __syncthreads();
    if (t < NCLS) {
        acc = b_out[t];
#pragma unroll 16
        for (int k = 0; k < 64; k++) acc += e2[k] * w_out[k * NCLS + t];
        out[t] = acc;
    }
}

extern "C" void kernel_launch(void* const* d_in, const int* in_sizes, int n_in,
                              void* d_out, int out_size, void* d_ws, size_t ws_size,
                              hipStream_t stream) {
    const float* freq   = (const float*)d_in[0];
    const float* flit   = (const float*)d_in[1];
    const float* op     = (const float*)d_in[2];
    const int* out_src  = (const int*)d_in[4];
    const int* in_dst   = (const int*)d_in[7];
    const int* pass_src = (const int*)d_in[8];
    const int* pass_dst = (const int*)d_in[9];
    const float* w_freq = (const float*)d_in[10];
    const float* b_freq = (const float*)d_in[11];
    const float* w_flit = (const float*)d_in[12];
    const float* b_flit = (const float*)d_in[13];
    const float* w_op   = (const float*)d_in[14];
    const float* b_op   = (const float*)d_in[15];
    const float* w_fp   = (const float*)d_in[18];
    const float* b_fp   = (const float*)d_in[19];
    const float* w_fr   = (const float*)d_in[20];
    const float* b_fr   = (const float*)d_in[21];
    const float* w_mp   = (const float*)d_in[24];
    const float* b_mp   = (const float*)d_in[25];
    const float* w_h1   = (const float*)d_in[26];
    const float* b_h1   = (const float*)d_in[27];
    const float* w_h2   = (const float*)d_in[28];
    const float* b_h2   = (const float*)d_in[29];
    const float* w_out  = (const float*)d_in[30];
    const float* b_out  = (const float*)d_in[31];
    float* out = (float*)d_out;

    char* ws = (char*)d_ws;
    float* pfeat_t     = (float*)(ws);                         // 64 MB
    float* hidden      = (float*)(ws + 67108864);              // 4 MB
    float* m           = (float*)(ws + 71303168);              // 4 MB
    float* embed       = (float*)(ws + 75497472);              // 4 KB (padded: 64 x 16 floats)
    float* packet_feat = (float*)(ws + 75502080);              // 2 MB (75497472+4608 aligned region)
    int*   deg         = (int*)  (ws + 77599232);
    int*   off         = (int*)  (ws + 77632000);
    int*   cursor      = (int*)  (ws + 77664768);
    int*   csr_ab      = (int*)  (ws + 77697536);

    // CSR build
    hipMemsetAsync(deg, 0, NP * sizeof(int), stream);
    k_hist<<<EP / 256, 256, 0, stream>>>(pass_src, deg);
    k_scan<<<1, 256, 0, stream>>>(deg, off, cursor);
    k_scatter<<<EP / 256, 256, 0, stream>>>(pass_src, pass_dst, out_src, in_dst, cursor, csr_ab);

    // Features
    k_packet<<<NP / 16, 256, 0, stream>>>(freq, flit, w_freq, b_freq, w_flit, b_flit, w_fp, b_fp, packet_feat);
    k_pfeat<<<dim3(NP / 64, 16), 256, 0, stream>>>(packet_feat, w_mp, b_mp, pfeat_t);
    k_router<<<NR / 16, 256, 0, stream>>>(op, w_op, b_op, w_fr, b_fr, hidden);

    // MP iteration 0 (k_update0 re-zeroes m for iteration 1)
    hipMemsetAsync(m, 0, NR * 64 * sizeof(float) + 64 * 16 * sizeof(float), stream);  // m + padded embed
    k_mp<<<NP / 4, 256, 0, stream>>>(pfeat_t, hidden, off, deg, csr_ab, m);
    k_update0<<<NR * 16 / 256, 256, 0, stream>>>(hidden, m);

    // MP iteration 1 (final: fused pooling, no hidden store)
    k_mp<<<NP / 4, 256, 0, stream>>>(pfeat_t, hidden, off, deg, csr_ab, m);
    k_update1<<<128, 256, 0, stream>>>(hidden, m, embed);

    // Head
    k_head<<<1, 64, 0, stream>>>(embed, w_h1, b_h1, w_h2, b_h2, w_out, b_out, out);
}

// Round 5
// 225.135 us; speedup vs baseline: 2.8284x; 1.0512x over previous
//
#include <hip/hip_runtime.h>

#define H_ 64
#define HD_ 32
#define NP 8192
#define NR 16384
#define NC 65536
#define EP 65536
#define NCLS 11

typedef unsigned short ushort_t;
typedef unsigned int uint_t;

__device__ inline uint_t packbf2(float lo, float hi) {
    uint_t a = __builtin_bit_cast(uint_t, lo);
    uint_t b = __builtin_bit_cast(uint_t, hi);
    a = (a + 0x7FFFu + ((a >> 16) & 1u)) >> 16;
    b = (b + 0x7FFFu + ((b >> 16) & 1u)) & 0xFFFF0000u;
    return a | b;
}

// ---------------- CSR build ----------------
__global__ void k_hist(const int* __restrict__ pass_src, int* __restrict__ deg) {
    int e = blockIdx.x * 256 + threadIdx.x;
    if (e < EP) atomicAdd(&deg[pass_src[e]], 1);
}

__global__ void k_scan(const int* __restrict__ deg, int* __restrict__ off, int* __restrict__ cursor) {
    __shared__ int sums[256];
    int t = threadIdx.x;
    int local[32];
    int s = 0;
#pragma unroll
    for (int i = 0; i < 32; i++) { local[i] = s; s += deg[t * 32 + i]; }
    sums[t] = s;
    __syncthreads();
    for (int ofs = 1; ofs < 256; ofs <<= 1) {
        int u = (t >= ofs) ? sums[t - ofs] : 0;
        __syncthreads();
        sums[t] += u;
        __syncthreads();
    }
    int base = sums[t] - s;
#pragma unroll
    for (int i = 0; i < 32; i++) {
        int v = base + local[i];
        off[t * 32 + i] = v;
        cursor[t * 32 + i] = v;
    }
}

__global__ void k_scatter(const int* __restrict__ pass_src, const int* __restrict__ pass_dst,
                          const int* __restrict__ out_src, const int* __restrict__ in_dst,
                          int* __restrict__ cursor, int* __restrict__ csr_ab) {
    int e = blockIdx.x * 256 + threadIdx.x;
    if (e < EP) {
        int p = pass_src[e];
        int c = pass_dst[e];
        int a = out_src[c];
        int b = in_dst[c];
        int pos = atomicAdd(&cursor[p], 1);
        csr_ab[pos] = (a << 14) | b;
    }
}

// ---------------- permute w_mp into GEMM-friendly, LDS-bank-friendly B' ----------------
// Logical GEMM col j' = d*64 + h  (so pfeat_b[p][j'] = pfeat[p][h][d]).
// Within each 128-col tile, physical col c holds logical j decoded by:
//   quad = c>>2, r = c&3; quad<16 ? j = quad*8 + r : j = (quad-16)*8 + 4 + r.
__global__ void k_perm(const float* __restrict__ w_mp, const float* __restrict__ b_mp,
                       float* __restrict__ Bp, float* __restrict__ biasp) {
    int i = blockIdx.x * 256 + threadIdx.x;  // over 64*2048
    int k = i >> 11, cg = i & 2047;
    int blk = cg >> 7, c = cg & 127;
    int quad = c >> 2, r = c & 3;
    int j = (quad < 16) ? (quad * 8 + r) : ((quad - 16) * 8 + 4 + r);
    int jp = blk * 128 + j;       // logical j' = d*64+h
    int d = jp >> 6, h = jp & 63;
    Bp[i] = w_mp[k * 2048 + h * 32 + d];
    if (i < 2048) biasp[i] = b_mp[h * 32 + d];  // i == cg here (k==0)
}

// ---------------- FeatureGen: routers -> hidden ----------------
__global__ __launch_bounds__(256) void k_router(const float* __restrict__ op,
                                                const float* __restrict__ w_op, const float* __restrict__ b_op,
                                                const float* __restrict__ w_fr, const float* __restrict__ b_fr,
                                                float* __restrict__ hidden) {
    __shared__ float s_wop[4 * 64];
    __shared__ float s_wfr[64 * 64];
    __shared__ float s_bop[64], s_bfr[64];
    __shared__ float s_tmp[16 * 64];
    int t = threadIdx.x;
    if (t < 64) { s_bop[t] = b_op[t]; s_bfr[t] = b_fr[t]; }
    if (t < 256) s_wop[t] = w_op[t];
    for (int i = t; i < 4096; i += 256) s_wfr[i] = w_fr[i];
    __syncthreads();
    int r0 = blockIdx.x * 16;
    for (int idx = t; idx < 16 * 64; idx += 256) {
        int row = idx >> 6, i = idx & 63;
        const float* o = op + (size_t)(r0 + row) * 4;
        float v = s_bop[i] + o[0] * s_wop[i] + o[1] * s_wop[64 + i] + o[2] * s_wop[128 + i] + o[3] * s_wop[192 + i];
        s_tmp[idx] = fmaxf(v, 0.f);
    }
    __syncthreads();
    for (int idx = t; idx < 16 * 64; idx += 256) {
        int row = idx >> 6, j = idx & 63;
        float acc = s_bfr[j];
        const float* tm = s_tmp + row * 64;
#pragma unroll 16
        for (int i = 0; i < 64; i++) acc += tm[i] * s_wfr[i * 64 + j];
        hidden[(size_t)(r0 + row) * 64 + j] = acc;
    }
}

// ---------------- FeatureGen: packets -> packet_feat ----------------
__global__ __launch_bounds__(256) void k_packet(const float* __restrict__ freq, const float* __restrict__ flit,
                                                const float* __restrict__ w_freq, const float* __restrict__ b_freq,
                                                const float* __restrict__ w_flit, const float* __restrict__ b_flit,
                                                const float* __restrict__ w_fp, const float* __restrict__ b_fp,
                                                float* __restrict__ pf) {
    __shared__ float s_wfl[32 * 64];
    __shared__ float s_wfp[128 * 64];
    __shared__ float s_tmp[16 * 128];
    __shared__ float s_wfq[64], s_bfq[64], s_bfl[64], s_bfp[64];
    int t = threadIdx.x;
    if (t < 64) { s_wfq[t] = w_freq[t]; s_bfq[t] = b_freq[t]; s_bfl[t] = b_flit[t]; s_bfp[t] = b_fp[t]; }
    for (int i = t; i < 2048; i += 256) s_wfl[i] = w_flit[i];
    for (int i = t; i < 8192; i += 256) s_wfp[i] = w_fp[i];
    __syncthreads();
    int r0 = blockIdx.x * 16;
    for (int idx = t; idx < 16 * 128; idx += 256) {
        int row = idx >> 7, i = idx & 127;
        float v;
        if (i < 64) {
            v = s_bfq[i] + freq[r0 + row] * s_wfq[i];
        } else {
            int ii = i - 64;
            float acc = s_bfl[ii];
            const float* f = flit + (size_t)(r0 + row) * 32;
#pragma unroll 8
            for (int k = 0; k < 32; k++) acc += f[k] * s_wfl[k * 64 + ii];
            v = acc;
        }
        s_tmp[idx] = fmaxf(v, 0.f);
    }
    __syncthreads();
    for (int idx = t; idx < 16 * 64; idx += 256) {
        int row = idx >> 6, j = idx & 63;
        float acc = s_bfp[j];
        const float* tm = s_tmp + row * 128;
#pragma unroll 16
        for (int i = 0; i < 128; i++) acc += tm[i] * s_wfp[i * 64 + j];
        pf[(size_t)(r0 + row) * 64 + j] = acc;
    }
}

// ---------------- pfeat_b[p][j'] (bf16) = pf @ B' + bias' ----------------
// Tile 64p x 128j, 256 threads, thread = (pg 0..15, jg 0..15) -> 4p x 8j.
__global__ __launch_bounds__(256) void k_pfeat(const float* __restrict__ pf, const float* __restrict__ Bp,
                                               const float* __restrict__ biasp, ushort_t* __restrict__ pfeat_b) {
    __shared__ float As[64 * 68];    // As[p][k], stride 68
    __shared__ float Bs[64 * 132];   // Bs[k][c],  stride 132 (c = permuted col)
    int t = threadIdx.x;
    int p0 = blockIdx.x * 64;
    int j0 = blockIdx.y * 128;
    // stage A: coalesced float4 both sides
#pragma unroll
    for (int it = 0; it < 4; it++) {
        int idx4 = t + it * 256;             // 1024 float4s
        int r = idx4 >> 4, kq = idx4 & 15;
        float4 v = *(const float4*)(pf + (size_t)(p0 + r) * 64 + kq * 4);
        *(float4*)(As + r * 68 + kq * 4) = v;
    }
    // stage B: coalesced float4 (permutation already baked into Bp)
#pragma unroll
    for (int it = 0; it < 8; it++) {
        int idx4 = t + it * 256;             // 2048 float4s
        int k = idx4 >> 5, c4 = idx4 & 31;
        float4 v = *(const float4*)(Bp + (size_t)k * 2048 + j0 + c4 * 4);
        *(float4*)(Bs + k * 132 + c4 * 4) = v;
    }
    __syncthreads();
    int pg = t >> 4, jg = t & 15;
    float acc0[8] = {}, acc1[8] = {}, acc2[8] = {}, acc3[8] = {};
    const float* asr = As + (pg * 4) * 68;
#pragma unroll 4
    for (int k = 0; k < 64; k++) {
        float4 w0 = *(const float4*)(Bs + k * 132 + jg * 4);        // logical j = jg*8+0..3
        float4 w1 = *(const float4*)(Bs + k * 132 + 64 + jg * 4);   // logical j = jg*8+4..7
        float a0 = asr[k], a1 = asr[68 + k], a2 = asr[136 + k], a3 = asr[204 + k];
        acc0[0] = fmaf(a0, w0.x, acc0[0]); acc0[1] = fmaf(a0, w0.y, acc0[1]);
        acc0[2] = fmaf(a0, w0.z, acc0[2]); acc0[3] = fmaf(a0, w0.w, acc0[3]);
        acc0[4] = fmaf(a0, w1.x, acc0[4]); acc0[5] = fmaf(a0, w1.y, acc0[5]);
        acc0[6] = fmaf(a0, w1.z, acc0[6]); acc0[7] = fmaf(a0, w1.w, acc0[7]);
        acc1[0] = fmaf(a1, w0.x, acc1[0]); acc1[1] = fmaf(a1, w0.y, acc1[1]);
        acc1[2] = fmaf(a1, w0.z, acc1[2]); acc1[3] = fmaf(a1, w0.w, acc1[3]);
        acc1[4] = fmaf(a1, w1.x, acc1[4]); acc1[5] = fmaf(a1, w1.y, acc1[5]);
        acc1[6] = fmaf(a1, w1.z, acc1[6]); acc1[7] = fmaf(a1, w1.w, acc1[7]);
        acc2[0] = fmaf(a2, w0.x, acc2[0]); acc2[1] = fmaf(a2, w0.y, acc2[1]);
        acc2[2] = fmaf(a2, w0.z, acc2[2]); acc2[3] = fmaf(a2, w0.w, acc2[3]);
        acc2[4] = fmaf(a2, w1.x, acc2[4]); acc2[5] = fmaf(a2, w1.y, acc2[5]);
        acc2[6] = fmaf(a2, w1.z, acc2[6]); acc2[7] = fmaf(a2, w1.w, acc2[7]);
        acc3[0] = fmaf(a3, w0.x, acc3[0]); acc3[1] = fmaf(a3, w0.y, acc3[1]);
        acc3[2] = fmaf(a3, w0.z, acc3[2]); acc3[3] = fmaf(a3, w0.w, acc3[3]);
        acc3[4] = fmaf(a3, w1.x, acc3[4]); acc3[5] = fmaf(a3, w1.y, acc3[5]);
        acc3[6] = fmaf(a3, w1.z, acc3[6]); acc3[7] = fmaf(a3, w1.w, acc3[7]);
    }
    float4 bb0 = *(const float4*)(biasp + j0 + jg * 4);
    float4 bb1 = *(const float4*)(biasp + j0 + 64 + jg * 4);
#define STORE_PP(ACC, PP) do { \
        uint4 v; \
        v.x = packbf2(ACC[0] + bb0.x, ACC[1] + bb0.y); \
        v.y = packbf2(ACC[2] + bb0.z, ACC[3] + bb0.w); \
        v.z = packbf2(ACC[4] + bb1.x, ACC[5] + bb1.y); \
        v.w = packbf2(ACC[6] + bb1.z, ACC[7] + bb1.w); \
        *(uint4*)(pfeat_b + (size_t)(p0 + pg * 4 + (PP)) * 2048 + j0 + jg * 8) = v; \
    } while (0)
    STORE_PP(acc0, 0);
    STORE_PP(acc1, 1);
    STORE_PP(acc2, 2);
    STORE_PP(acc3, 3);
#undef STORE_PP
}

// ---------------- Message passing ----------------
// wave per packet; lane = (hi,d); preg[m] = pfeat[p][h=hi*32+m][d] (bf16->f32).
// 2-deep ping-pong prefetch of hidden rows; csr loads are scalar (wid uniform).
__global__ __launch_bounds__(256) void k_mp(const ushort_t* __restrict__ pfeat_b, const float* __restrict__ hidden,
                                            const int* __restrict__ off, const int* __restrict__ deg,
                                            const int* __restrict__ csr_ab, float* __restrict__ m) {
    int wid = __builtin_amdgcn_readfirstlane((blockIdx.x << 2) + (threadIdx.x >> 6));
    int lane = threadIdx.x & 63;
    int hi = lane >> 5, d = lane & 31;
    const uint4* pr = (const uint4*)(pfeat_b + (size_t)wid * 2048 + d * 64 + hi * 32);
    float preg[32];
#pragma unroll
    for (int q = 0; q < 4; q++) {
        uint4 u = pr[q];
        preg[q * 8 + 0] = __builtin_bit_cast(float, u.x << 16);
        preg[q * 8 + 1] = __builtin_bit_cast(float, u.x & 0xFFFF0000u);
        preg[q * 8 + 2] = __builtin_bit_cast(float, u.y << 16);
        preg[q * 8 + 3] = __builtin_bit_cast(float, u.y & 0xFFFF0000u);
        preg[q * 8 + 4] = __builtin_bit_cast(float, u.z << 16);
        preg[q * 8 + 5] = __builtin_bit_cast(float, u.z & 0xFFFF0000u);
        preg[q * 8 + 6] = __builtin_bit_cast(float, u.w << 16);
        preg[q * 8 + 7] = __builtin_bit_cast(float, u.w & 0xFFFF0000u);
    }
    int e0 = off[wid];
    int n = deg[wid];
    if (n <= 0) return;
    const float4* hb4 = (const float4*)hidden;

#define LOADX(XA, XB, PK) do { \
        int a_ = (PK) >> 14, b_ = (PK) & 16383; \
        const float4* qa_ = hb4 + a_ * 16 + hi * 8; \
        const float4* qb_ = hb4 + b_ * 16 + hi * 8; \
        _Pragma("unroll") for (int q = 0; q < 8; q++) XA[q] = qa_[q]; \
        _Pragma("unroll") for (int q = 0; q < 8; q++) XB[q] = qb_[q]; \
    } while (0)

#define COMPUTE(XA, XB, PK) do { \
        int a_ = (PK) >> 14, b_ = (PK) & 16383; \
        float vi0 = 0, vi1 = 0, vi2 = 0, vi3 = 0, vo0 = 0, vo1 = 0, vo2 = 0, vo3 = 0; \
        _Pragma("unroll") for (int q = 0; q < 8; q++) { \
            vi0 = fmaf(preg[4 * q + 0], XA[q].x, vi0); \
            vi1 = fmaf(preg[4 * q + 1], XA[q].y, vi1); \
            vi2 = fmaf(preg[4 * q + 2], XA[q].z, vi2); \
            vi3 = fmaf(preg[4 * q + 3], XA[q].w, vi3); \
            vo0 = fmaf(preg[4 * q + 0], XB[q].x, vo0); \
            vo1 = fmaf(preg[4 * q + 1], XB[q].y, vo1); \
            vo2 = fmaf(preg[4 * q + 2], XB[q].z, vo2); \
            vo3 = fmaf(preg[4 * q + 3], XB[q].w, vo3); \
        } \
        float vin = (vi0 + vi1) + (vi2 + vi3); \
        float vout = (vo0 + vo1) + (vo2 + vo3); \
        vin += __shfl_xor(vin, 32); \
        vout += __shfl_xor(vout, 32); \
        if (hi == 0) atomicAdd(&m[(size_t)b_ * 64 + d], vin); \
        else atomicAdd(&m[(size_t)a_ * 64 + 32 + d], vout); \
    } while (0)

    float4 xa0[8], xb0[8], xa1[8], xb1[8];
    int pk0 = csr_ab[e0];
    LOADX(xa0, xb0, pk0);
    int pk1 = 0;
    if (n > 1) { pk1 = csr_ab[e0 + 1]; LOADX(xa1, xb1, pk1); }
    int i = 0;
    while (true) {
        COMPUTE(xa0, xb0, pk0);
        if (i + 2 < n) { pk0 = csr_ab[e0 + i + 2]; LOADX(xa0, xb0, pk0); }
        if (i + 1 >= n) break;
        COMPUTE(xa1, xb1, pk1);
        if (i + 3 < n) { pk1 = csr_ab[e0 + i + 3]; LOADX(xa1, xb1, pk1); }
        if (i + 2 >= n) break;
        i += 2;
    }
#undef LOADX
#undef COMPUTE
}

// ---------------- update: hidden = relu(hidden + m) ----------------
__global__ __launch_bounds__(256) void k_update0(float* __restrict__ hidden, float* __restrict__ m) {
    int i = blockIdx.x * 256 + threadIdx.x;  // exactly NR*16 threads
    float4* h4 = (float4*)hidden;
    float4* m4 = (float4*)m;
    float4 hv = h4[i];
    float4 mv = m4[i];
    float4 v;
    v.x = fmaxf(hv.x + mv.x, 0.f);
    v.y = fmaxf(hv.y + mv.y, 0.f);
    v.z = fmaxf(hv.z + mv.z, 0.f);
    v.w = fmaxf(hv.w + mv.w, 0.f);
    h4[i] = v;
    m4[i] = make_float4(0.f, 0.f, 0.f, 0.f);
}

// Final: fused column-sum pooling into line-padded embed (stride 16 floats).
__global__ __launch_bounds__(256) void k_update1(const float* __restrict__ hidden, const float* __restrict__ m,
                                                 float* __restrict__ embed) {
    int t = threadIdx.x;
    int base = blockIdx.x * 256 + t;
    const float4* h4 = (const float4*)hidden;
    const float4* m4 = (const float4*)m;
    float col[4] = {0.f, 0.f, 0.f, 0.f};
    for (int i = base; i < NR * 16; i += 128 * 256) {
        float4 hv = h4[i];
        float4 mv = m4[i];
        col[0] += fmaxf(hv.x + mv.x, 0.f);
        col[1] += fmaxf(hv.y + mv.y, 0.f);
        col[2] += fmaxf(hv.z + mv.z, 0.f);
        col[3] += fmaxf(hv.w + mv.w, 0.f);
    }
#pragma unroll
    for (int k = 0; k < 4; k++) {
        col[k] += __shfl_xor(col[k], 16);
        col[k] += __shfl_xor(col[k], 32);
    }
    __shared__ float scol[4][64];
    int w = t >> 6, lane = t & 63;
    if (lane < 16) {
#pragma unroll
        for (int k = 0; k < 4; k++) scol[w][lane * 4 + k] = col[k];
    }
    __syncthreads();
    if (t < 64) {
        float s = scol[0][t] + scol[1][t] + scol[2][t] + scol[3][t];
        atomicAdd(&embed[t * 16], s);
    }
}

// ---------------- prediction head ----------------
__global__ void k_head(const float* __restrict__ embed,
                       const float* __restrict__ w_h1, const float* __restrict__ b_h1,
                       const float* __restrict__ w_h2, const float* __restrict__ b_h2,
                       const float* __restrict__ w_out, const float* __restrict__ b_out,
                       float* __restrict__ out) {
    __shared__ float e1[64], e2[64];
    int t = threadIdx.x;
    float acc = b_h1[t];
#pragma unroll 16
    for (int k = 0; k < 64; k++) acc += embed[k * 16] * w_h1[k * 64 + t];
    e1[t] = fmaxf(acc, 0.f);
    __syncthreads();
    acc = b_h2[t];
#pragma unroll 16
    for (int k = 0; k < 64; k++) acc += e1[k] * w_h2[k * 64 + t];
    e2[t] = fmaxf(acc, 0.f);
    __syncthreads();
    if (t < NCLS) {
        acc = b_out[t];
#pragma unroll 16
        for (int k = 0; k < 64; k++) acc += e2[k] * w_out[k * NCLS + t];
        out[t] = acc;
    }
}

extern "C" void kernel_launch(void* const* d_in, const int* in_sizes, int n_in,
                              void* d_out, int out_size, void* d_ws, size_t ws_size,
                              hipStream_t stream) {
    const float* freq   = (const float*)d_in[0];
    const float* flit   = (const float*)d_in[1];
    const float* op     = (const float*)d_in[2];
    const int* out_src  = (const int*)d_in[4];
    const int* in_dst   = (const int*)d_in[7];
    const int* pass_src = (const int*)d_in[8];
    const int* pass_dst = (const int*)d_in[9];
    const float* w_freq = (const float*)d_in[10];
    const float* b_freq = (const float*)d_in[11];
    const float* w_flit = (const float*)d_in[12];
    const float* b_flit = (const float*)d_in[13];
    const float* w_op   = (const float*)d_in[14];
    const float* b_op   = (const float*)d_in[15];
    const float* w_fp   = (const float*)d_in[18];
    const float* b_fp   = (const float*)d_in[19];
    const float* w_fr   = (const float*)d_in[20];
    const float* b_fr   = (const float*)d_in[21];
    const float* w_mp   = (const float*)d_in[24];
    const float* b_mp   = (const float*)d_in[25];
    const float* w_h1   = (const float*)d_in[26];
    const float* b_h1   = (const float*)d_in[27];
    const float* w_h2   = (const float*)d_in[28];
    const float* b_h2   = (const float*)d_in[29];
    const float* w_out  = (const float*)d_in[30];
    const float* b_out  = (const float*)d_in[31];
    float* out = (float*)d_out;

    char* ws = (char*)d_ws;
    ushort_t* pfeat_b  = (ushort_t*)(ws);                  // 32 MB
    float* hidden      = (float*)(ws + 33554432);          // 4 MB
    float* m           = (float*)(ws + 37748736);          // 4 MB
    float* embed       = (float*)(ws + 41943040);          // 4 KB (64 x 16 floats, line-padded)
    float* packet_feat = (float*)(ws + 41947136);          // 2 MB
    float* Bp          = (float*)(ws + 44044288);          // 512 KB
    float* biasp       = (float*)(ws + 44568576);          // 8 KB
    int*   deg         = (int*)  (ws + 44576768);          // 32 KB
    int*   off         = (int*)  (ws + 44609536);          // 32 KB
    int*   cursor      = (int*)  (ws + 44642304);          // 32 KB
    int*   csr_ab      = (int*)  (ws + 44675072);          // 256 KB

    // CSR build
    hipMemsetAsync(deg, 0, NP * sizeof(int), stream);
    k_hist<<<EP / 256, 256, 0, stream>>>(pass_src, deg);
    k_scan<<<1, 256, 0, stream>>>(deg, off, cursor);
    k_scatter<<<EP / 256, 256, 0, stream>>>(pass_src, pass_dst, out_src, in_dst, cursor, csr_ab);

    // Weight permutation + features
    k_perm<<<512, 256, 0, stream>>>(w_mp, b_mp, Bp, biasp);
    k_packet<<<NP / 16, 256, 0, stream>>>(freq, flit, w_freq, b_freq, w_flit, b_flit, w_fp, b_fp, packet_feat);
    k_pfeat<<<dim3(NP / 64, 16), 256, 0, stream>>>(packet_feat, Bp, biasp, pfeat_b);
    k_router<<<NR / 16, 256, 0, stream>>>(op, w_op, b_op, w_fr, b_fr, hidden);

    // MP iteration 0 (k_update0 re-zeroes m for iteration 1)
    hipMemsetAsync(m, 0, NR * 64 * sizeof(float) + 4096, stream);  // m + padded embed
    k_mp<<<NP / 4, 256, 0, stream>>>(pfeat_b, hidden, off, deg, csr_ab, m);
    k_update0<<<NR * 16 / 256, 256, 0, stream>>>(hidden, m);

    // MP iteration 1 (final: fused pooling, no hidden store)
    k_mp<<<NP / 4, 256, 0, stream>>>(pfeat_b, hidden, off, deg, csr_ab, m);
    k_update1<<<128, 256, 0, stream>>>(hidden, m, embed);

    // Head
    k_head<<<1, 64, 0, stream>>>(embed, w_h1, b_h1, w_h2, b_h2, w_out, b_out, out);
}